// Round 9
// baseline (215.441 us; speedup 1.0000x reference)
//
#include <hip/hip_runtime.h>
#include <math.h>

// B=8, N=2048, Fin=Fout=512, fp32 in/out. bf16 MFMA internally.
// Algebra: adj = X·(w1^T w2)·X^T  ->  precompute V = w2^T·w1 (512x512, scaled
// by log2e), Y = X·V^T, E = exp2(Y·X^T), column-softmax via D colsums,
// out = E·(sup/D) + bias.
#define BB 8
#define NN 2048
#define FF 512
#define LOG2E 1.4426950408889634f

typedef __attribute__((ext_vector_type(8))) short short8;
typedef __attribute__((ext_vector_type(4))) float floatx4;
typedef __attribute__((ext_vector_type(2))) float float2v;
typedef __attribute__((ext_vector_type(2))) __bf16 bf16x2;

__device__ __forceinline__ unsigned short f2bf(float f) {
    union { float f; unsigned u; } v; v.f = f;
    unsigned r = v.u + 0x7FFFu + ((v.u >> 16) & 1u);
    return (unsigned short)(r >> 16);
}

__device__ __forceinline__ float fexp2(float x) {
#if __has_builtin(__builtin_amdgcn_exp2f)
    return __builtin_amdgcn_exp2f(x);
#else
    return __expf(x * 0.69314718056f);
#endif
}

__device__ __forceinline__ void pk_store(unsigned short* p0, unsigned short* p1,
                                         float a, float b) {
    union { bf16x2 h; unsigned short s[2]; } u;
    float2v v; v.x = a; v.y = b;
    u.h = __builtin_convertvector(v, bf16x2);
    *p0 = u.s[0]; *p1 = u.s[1];
}

#define BAR() __builtin_amdgcn_s_barrier()
#define LGKM0() do { asm volatile("s_waitcnt lgkmcnt(0)" ::: "memory"); \
                     __builtin_amdgcn_sched_barrier(0); } while (0)
#define GLDS(src, dst) __builtin_amdgcn_global_load_lds( \
    (const __attribute__((address_space(1))) void*)(src), \
    (__attribute__((address_space(3))) void*)(dst), 16, 0, 0)
#define VMW(n) asm volatile("s_waitcnt vmcnt(" #n ")" ::: "memory")

// ---------------------------------------------------------------------------
// 4-phase BT-GEMM (r9): C[i,j] = sum_k A[i*a_ld+k]*B[j*b_ld+k]
// Tile BM x 256 (BM = M_REP*32), 512 thr = 8 waves (2M x 4N).
// BK=64 in two 32-k halves; 4 rotating LDS slots per matrix [khalf][parity].
// Each phase = one (tile, k-half) at FULL N width: reads RA + 4 B-frags,
// stages ONE full half-tile batch (A+B), counted VMW every phase, barrier,
// lgkm0, M_REP*4 MFMA (32 @M_REP=8), barrier.  Half the barriers of the r6-r8
// 8-phase structure (r8 PMC: ~1400 cyc/phase fixed overhead dominates).
// Ledger (hand-verified; batch = LA+2 loads):
//  stage map: ph1->(t+1,k1)->slots[1][1]; ph2->(t+2,k0)->[0][0];
//             ph3->(t+2,k1)->[1][0]; ph4->(t+3,k0)->[0][1].
//  overwrite: each stage's target slot was read in the immediately preceding
//   phase; those reads are lgkm-drained before that phase's MFMA and the
//   stage issues after its trailing barrier. SAFE.
//  publish: VMW(2*batch) at every phase keeps exactly 2 batches in flight;
//   a batch staged at phase q is drained at q+2's VMW (+barrier) and first
//   read at q+3 (reads issue after B2(q+2)). SAFE.
//  steady outstanding chain: ph1:[p3,p4,b1]->drain p3; ph2:[p4,b1,b2]->p4;
//   ph3:[b1,b2,b3]->b1 (read ph4); ph4:[b2,b3,b4]->b2 (read nph1).
//  prologue: 3 batches (t0k0,t0k1,t1k0), VMW(2*batch) drains t0k0.
//  last iter: ph1 stages (t+1,k1) as usual; ph2 VMW(batch) drains (t+1,k0);
//   ph3 VMW(0) drains ph1's batch; ph4 none outstanding.
// LDS chunk-XOR swizzle (counter-verified 0 conflicts r2-r8).
// Epilogue modes 1/2: LDS-restage + coalesced short8 readout. XCD swizzle.
// modes: 0 = fp32 out + bias[j]; 1 = bf16 out; 2 = bf16 exp2(out) + Dsum.
// Requires K % 128 == 0, K >= 256; exact grid tiling.
// ---------------------------------------------------------------------------
template<int M_REP, int MODE>
__global__ __launch_bounds__(512) void gemm256(
    const unsigned short* __restrict__ A, const unsigned short* __restrict__ B,
    void* __restrict__ Cv, const float* __restrict__ bias, float* __restrict__ Dsum,
    int K, int a_ld, int b_ld, int ldc,
    long a_batch, long b_batch, long c_batch)
{
    constexpr int BM    = M_REP * 32;
    constexpr int LA    = BM / 128;
    constexpr int ASLOT = BM * 32;
    constexpr int BSLOT = 256 * 32;
    __shared__ __align__(16) unsigned short SH[4 * ASLOT + 4 * BSLOT];

    const int tid  = threadIdx.x;
    const int wave = tid >> 6;
    const int lane = tid & 63;
    const int wr   = wave >> 2;
    const int wc   = wave & 3;
    const int fl   = lane & 15;
    const int quad = lane >> 4;

    const int gx = gridDim.x, gy = gridDim.y;
    int flat = blockIdx.x + gx * (blockIdx.y + gy * blockIdx.z);
    const int cpx = (gx * gy * gridDim.z) >> 3;
    if (cpx > 0) flat = (flat & 7) * cpx + (flat >> 3);
    const int bx = flat % gx;
    const int rest = flat / gx;
    const int by = rest % gy;
    const int bz = rest / gy;

    const int m0 = by * BM;
    const int n0 = bx * 256;

    const unsigned short* Aptr = A + (long)bz * a_batch + (long)m0 * a_ld;
    const unsigned short* Bptr = B + (long)bz * b_batch + (long)n0 * b_ld;

    int offA[LA], offB[2];
    #pragma unroll
    for (int i = 0; i < LA; ++i) {
        const int cl = i * 512 + tid;
        const int r = cl >> 2, s = cl & 3;
        offA[i] = r * a_ld + (s ^ ((r >> 1) & 3)) * 8;
    }
    #pragma unroll
    for (int i = 0; i < 2; ++i) {
        const int cl = i * 512 + tid;
        const int r = cl >> 2, s = cl & 3;
        offB[i] = r * b_ld + (s ^ ((r >> 1) & 3)) * 8;
    }

    const int swz = (quad ^ ((fl >> 1) & 3)) * 8;
    const int aRd = (wr * (M_REP * 16) + fl) * 32 + swz;
    const int bRd = (wc * 64 + fl) * 32 + swz;

    auto sA = [&](int kh, int db, int kb) {
        #pragma unroll
        for (int i = 0; i < LA; ++i)
            GLDS(Aptr + kb + offA[i], &SH[(kh * 2 + db) * ASLOT + (i * 512 + tid) * 8]);
    };
    auto sB = [&](int kh, int db, int kb) {
        #pragma unroll
        for (int i = 0; i < 2; ++i)
            GLDS(Bptr + kb + offB[i], &SH[4 * ASLOT + (kh * 2 + db) * BSLOT + (i * 512 + tid) * 8]);
    };

    floatx4 acc[M_REP][4] = {};
    short8 af[M_REP], bf[4];

    auto RA = [&](int kh, int db) {
        const unsigned short* b = &SH[(kh * 2 + db) * ASLOT + aRd];
        #pragma unroll
        for (int m = 0; m < M_REP; ++m) af[m] = *(const short8*)(b + m * 512);
    };
    auto RB4 = [&](int kh, int db) {
        const unsigned short* b = &SH[4 * ASLOT + (kh * 2 + db) * BSLOT + bRd];
        bf[0] = *(const short8*)(b);
        bf[1] = *(const short8*)(b + 512);
        bf[2] = *(const short8*)(b + 1024);
        bf[3] = *(const short8*)(b + 1536);
    };
    auto MCF = [&]() {
        __builtin_amdgcn_s_setprio(1);
        #pragma unroll
        for (int m = 0; m < M_REP; ++m)
            #pragma unroll
            for (int j = 0; j < 4; ++j)
                acc[m][j] = __builtin_amdgcn_mfma_f32_16x16x32_bf16(af[m], bf[j], acc[m][j], 0, 0, 0);
        __builtin_amdgcn_s_setprio(0);
    };

    const int nt = K >> 6;
    const int ni = nt >> 1;

    // prologue: batches (t0,k0), (t0,k1), (t1,k0); drain first, keep 2
    sA(0, 0, 0);  sB(0, 0, 0);
    sA(1, 0, 32); sB(1, 0, 32);
    sA(0, 1, 64); sB(0, 1, 64);
    if constexpr (LA == 2) VMW(8); else VMW(6);
    BAR();

    for (int i = 0; i < ni; ++i) {
        const bool last = (i == ni - 1);
        const int kb1 = (2 * i + 1) * 64, kb2 = kb1 + 64, kb3 = kb2 + 64;

        // ph1: (t,k0); stage (t+1,k1)
        RA(0, 0); RB4(0, 0);
        sA(1, 1, kb1 + 32); sB(1, 1, kb1 + 32);
        if constexpr (LA == 2) VMW(8); else VMW(6);
        BAR(); LGKM0(); MCF(); BAR();

        // ph2: (t,k1); stage (t+2,k0)
        RA(1, 0); RB4(1, 0);
        if (!last) {
            sA(0, 0, kb2); sB(0, 0, kb2);
            if constexpr (LA == 2) VMW(8); else VMW(6);
        } else {
            if constexpr (LA == 2) VMW(4); else VMW(3);
        }
        BAR(); LGKM0(); MCF(); BAR();

        // ph3: (t+1,k0); stage (t+2,k1)
        RA(0, 1); RB4(0, 1);
        if (!last) {
            sA(1, 0, kb2 + 32); sB(1, 0, kb2 + 32);
            if constexpr (LA == 2) VMW(8); else VMW(6);
        } else {
            VMW(0);
        }
        BAR(); LGKM0(); MCF(); BAR();

        // ph4: (t+1,k1); stage (t+3,k0)
        RA(1, 1); RB4(1, 1);
        if (!last) {
            sA(0, 1, kb3); sB(0, 1, kb3);
            if constexpr (LA == 2) VMW(8); else VMW(6);
        }
        BAR(); LGKM0(); MCF(); BAR();
    }

    const int wmg = m0 + wr * (M_REP * 16);
    const int wcol = wc * 64;

    if constexpr (MODE == 0) {
        float* Cb = (float*)Cv + (long)bz * c_batch;
        #pragma unroll
        for (int n = 0; n < 4; ++n) {
            const int ng = n0 + wcol + n * 16 + fl;
            const float badd = bias ? bias[ng] : 0.0f;
            #pragma unroll
            for (int m = 0; m < M_REP; ++m) {
                const int mg = wmg + m * 16 + quad * 4;
                #pragma unroll
                for (int r = 0; r < 4; ++r)
                    Cb[(long)(mg + r) * ldc + ng] = acc[m][n][r] + badd;
            }
        }
    } else {
        unsigned short* Cb = (unsigned short*)Cv + (long)bz * c_batch;
        if constexpr (MODE == 2) {
            float* Db = Dsum + (long)bz * NN;
            #pragma unroll
            for (int m = 0; m < M_REP; ++m)
                #pragma unroll
                for (int n = 0; n < 4; ++n)
                    #pragma unroll
                    for (int r = 0; r < 4; ++r)
                        acc[m][n][r] = fexp2(acc[m][n][r]);
            #pragma unroll
            for (int n = 0; n < 4; ++n) {
                float csum = 0.f;
                #pragma unroll
                for (int m = 0; m < M_REP; ++m)
                    csum += acc[m][n][0] + acc[m][n][1] + acc[m][n][2] + acc[m][n][3];
                csum += __shfl_xor(csum, 16);
                csum += __shfl_xor(csum, 32);
                if (quad == 0) atomicAdd(&Db[n0 + wcol + n * 16 + fl], csum);
            }
        }
        __syncthreads();
        #pragma unroll
        for (int m = 0; m < M_REP; ++m) {
            const int rowb = wr * (M_REP * 16) + m * 16 + quad * 4;
            #pragma unroll
            for (int n = 0; n < 4; ++n) {
                const int pc = (wcol + n * 16 + fl) ^ (quad << 4);
                #pragma unroll
                for (int r = 0; r < 4; ++r)
                    SH[(rowb + r) * 256 + pc] = f2bf(acc[m][n][r]);
            }
        }
        __syncthreads();
        #pragma unroll
        for (int k = 0; k < M_REP * 2; ++k) {
            const int idx = k * 512 + tid;
            const int row = idx >> 5, c8 = (idx & 31) * 8;
            const int lcol = c8 ^ (((row >> 2) & 3) << 4);
            short8 vv = *(const short8*)&SH[row * 256 + lcol];
            *(short8*)&Cb[(long)(m0 + row) * ldc + n0 + c8] = vv;
        }
    }
}

// ---------------------------------------------------------------------------
// Small 128x128-tile BT-GEMM (r0 verified core), bf16 out. For V = w2T·w1T^T:
// 512x512x512 on 16 blocks.
// ---------------------------------------------------------------------------
__global__ __launch_bounds__(256) void gemm128_bt(
    const unsigned short* __restrict__ A, const unsigned short* __restrict__ B,
    unsigned short* __restrict__ C, int K, int a_ld, int b_ld, int ldc)
{
    __shared__ __align__(16) unsigned short Alds[128 * 64];
    __shared__ __align__(16) unsigned short Blds[128 * 64];

    const int tid  = threadIdx.x;
    const int wave = tid >> 6;
    const int lane = tid & 63;
    const int m0 = blockIdx.y * 128;
    const int n0 = blockIdx.x * 128;

    const unsigned short* Aptr = A + (long)m0 * a_ld;
    const unsigned short* Bptr = B + (long)n0 * b_ld;

    const int wm   = (wave >> 1) * 64;
    const int wn   = (wave & 1) * 64;
    const int fl   = lane & 15;
    const int quad = lane >> 4;

    int offA[4], offB[4], cb[4];
    #pragma unroll
    for (int issue = 0; issue < 4; ++issue) {
        const int cbase = issue * 256 + wave * 64;
        const int c = cbase + lane;
        const int row = c >> 3;
        const int kq = ((c & 7) ^ ((c >> 3) & 7)) * 8;
        offA[issue] = row * a_ld + kq;
        offB[issue] = row * b_ld + kq;
        cb[issue] = cbase * 8;
    }

    floatx4 acc[4][4] = {};

    for (int k0 = 0; k0 < K; k0 += 64) {
        #pragma unroll
        for (int issue = 0; issue < 4; ++issue) {
            GLDS(Aptr + offA[issue], &Alds[cb[issue] + lane * 8]);
            GLDS(Bptr + offB[issue], &Blds[cb[issue] + lane * 8]);
        }
        Aptr += 64; Bptr += 64;
        __syncthreads();

        #pragma unroll
        for (int s = 0; s < 2; ++s) {
            short8 af[4], bfr[4];
            const int slot = ((s * 4 + quad) ^ (fl & 7)) * 8;
            #pragma unroll
            for (int i = 0; i < 4; ++i)
                af[i] = *(const short8*)&Alds[(wm + i * 16 + fl) * 64 + slot];
            #pragma unroll
            for (int j = 0; j < 4; ++j)
                bfr[j] = *(const short8*)&Blds[(wn + j * 16 + fl) * 64 + slot];
            #pragma unroll
            for (int i = 0; i < 4; ++i)
                #pragma unroll
                for (int j = 0; j < 4; ++j)
                    acc[i][j] = __builtin_amdgcn_mfma_f32_16x16x32_bf16(af[i], bfr[j], acc[i][j], 0, 0, 0);
        }
        __syncthreads();
    }

    #pragma unroll
    for (int j = 0; j < 4; ++j) {
        const int ng = n0 + wn + j * 16 + fl;
        #pragma unroll
        for (int i = 0; i < 4; ++i) {
            const int mg = m0 + wm + i * 16 + quad * 4;
            pk_store(&C[(long)(mg + 0) * ldc + ng], &C[(long)(mg + 1) * ldc + ng],
                     acc[i][j][0], acc[i][j][1]);
            pk_store(&C[(long)(mg + 2) * ldc + ng], &C[(long)(mg + 3) * ldc + ng],
                     acc[i][j][2], acc[i][j][3]);
        }
    }
}

// ---------------------------------------------------------------------------
// Fused prep: [0,4096) x->bf16 | [4096,4864) three 512x512 transposes
// (w1*log2e, w2, weight) | [4864,4928) Dsum zero.  One dispatch.
// ---------------------------------------------------------------------------
__global__ __launch_bounds__(256) void prep_all(
    const float* __restrict__ x, const float* __restrict__ w1,
    const float* __restrict__ w2, const float* __restrict__ w,
    unsigned short* __restrict__ xb, unsigned short* __restrict__ w1T,
    unsigned short* __restrict__ w2T, unsigned short* __restrict__ wT,
    float* __restrict__ Dsum)
{
    __shared__ float tl[32][33];
    int b = blockIdx.x;
    if (b < 4096) {
        const long i = ((long)b * 256 + threadIdx.x) * 8;
        float4 a = *(const float4*)(x + i);
        float4 c = *(const float4*)(x + i + 4);
        union { bf16x2 h[4]; short8 s8; } u;
        float2v v;
        v.x = a.x; v.y = a.y; u.h[0] = __builtin_convertvector(v, bf16x2);
        v.x = a.z; v.y = a.w; u.h[1] = __builtin_convertvector(v, bf16x2);
        v.x = c.x; v.y = c.y; u.h[2] = __builtin_convertvector(v, bf16x2);
        v.x = c.z; v.y = c.w; u.h[3] = __builtin_convertvector(v, bf16x2);
        *(short8*)(xb + i) = u.s8;
        return;
    }
    b -= 4096;
    if (b < 768) {
        const float* in; unsigned short* out; float sc = 1.0f;
        const int seg = b >> 8, t = b & 255;
        if (seg == 0)      { in = w1; out = w1T; sc = LOG2E; }
        else if (seg == 1) { in = w2; out = w2T; }
        else               { in = w;  out = wT; }
        const int tx = threadIdx.x & 31, ty = threadIdx.x >> 5;
        const int x0 = (t & 15) * 32, y0 = (t >> 4) * 32;
        #pragma unroll
        for (int k = 0; k < 32; k += 8)
            tl[ty + k][tx] = in[(long)(y0 + ty + k) * FF + x0 + tx];
        __syncthreads();
        #pragma unroll
        for (int k = 0; k < 32; k += 8)
            out[(long)(x0 + ty + k) * FF + y0 + tx] = f2bf(tl[tx][ty + k] * sc);
        return;
    }
    b -= 768;
    Dsum[(long)b * 256 + threadIdx.x] = 0.0f;
}

// supT[o,m] = bf16( sup[m,o] / D[m] ); sup[m,o] = Call[m*1024 + 512 + o] (bf16).
__global__ __launch_bounds__(256) void scale_transpose(
    const unsigned short* __restrict__ Call, const float* __restrict__ D,
    unsigned short* __restrict__ supT, int batch0)
{
    __shared__ float t[32][33];
    __shared__ float rD[32];
    const int tx = threadIdx.x & 31, ty = threadIdx.x >> 5;
    const int mt = blockIdx.x * 32, ot = blockIdx.y * 32;
    const int b = batch0 + blockIdx.z;
    const unsigned short* Cb = Call + (long)b * NN * 1024;
    unsigned short* Tb = supT + (long)b * NN * FF;
    if (threadIdx.x < 32) rD[threadIdx.x] = 1.0f / D[(long)b * NN + mt + threadIdx.x];
    __syncthreads();
    #pragma unroll
    for (int k = 0; k < 32; k += 8) {
        unsigned short u = Cb[(long)(mt + ty + k) * 1024 + 512 + ot + tx];
        union { unsigned uu; float f; } cv; cv.uu = ((unsigned)u) << 16;
        t[ty + k][tx] = cv.f;
    }
    __syncthreads();
    #pragma unroll
    for (int k = 0; k < 32; k += 8)
        Tb[(long)(ot + ty + k) * NN + mt + tx] = f2bf(t[tx][ty + k] * rD[tx]);
}

extern "C" void kernel_launch(void* const* d_in, const int* in_sizes, int n_in,
                              void* d_out, int out_size, void* d_ws, size_t ws_size,
                              hipStream_t stream)
{
    const float* x      = (const float*)d_in[0];
    const float* weight = (const float*)d_in[1];
    const float* bias   = (const float*)d_in[2];
    const float* w_one  = (const float*)d_in[3];
    const float* w_two  = (const float*)d_in[4];
    float* out = (float*)d_out;

    const long NF  = (long)NN * FF;      // 1,048,576
    const long NN2 = (long)NN * NN;      // 4,194,304
    const long CROW = 1024;              // C_all row stride (Y | sup)

    // workspace carve
    char* p = (char*)d_ws;
    unsigned short* xb    = (unsigned short*)p; p += (size_t)BB * NF * 2;          // 16 MB
    unsigned short* Wg1   = (unsigned short*)p; p += (size_t)1024 * FF * 2;        // 1 MB  [V ; wT]
    unsigned short* w1T   = (unsigned short*)p; p += (size_t)FF * FF * 2;          // 0.5 MB
    unsigned short* w2T   = (unsigned short*)p; p += (size_t)FF * FF * 2;          // 0.5 MB
    unsigned short* Call  = (unsigned short*)p; p += (size_t)BB * NN * CROW * 2;   // 32 MB
    unsigned short* supT  = (unsigned short*)p; p += (size_t)BB * NF * 2;          // 16 MB
    float*          Dsum  = (float*)p;          p += (size_t)BB * NN * 4;          // 64 KB
    unsigned short* E     = (unsigned short*)p;                                    // 64 MB (full) or 8 MB (batch)
    unsigned short* Vw  = Wg1;                       // rows 0..511: V = w2^T·w1·log2e
    unsigned short* wTb = Wg1 + (size_t)FF * FF;     // rows 512..1023: weight^T

    const size_t fixed = (size_t)(p - (char*)d_ws);
    const bool full = ws_size >= fixed + (size_t)BB * NN2 * 2;

    dim3 blk(256), blk5(512);

    // 1) fused prep: x->bf16, w1T(log2e)/w2T/wT transposes, Dsum zero
    prep_all<<<dim3(4928), blk, 0, stream>>>(
        x, w_one, w_two, weight, xb, w1T, w2T, wTb, Dsum);

    // 2) V[g,f] = w2T[g,:]·w1T[f,:]  — 128² tiles, 16 blocks
    gemm128_bt<<<dim3(FF / 128, FF / 128), blk, 0, stream>>>(
        w2T, w1T, Vw, FF, FF, FF, FF);

    // 3) Call[n,:] = [ Y = X·V^T | sup = X·W ]  — (4,8,8) = 256 blocks, 1 round
    gemm256<8, 1><<<dim3(1024 / 256, NN / 256, BB), blk5, 0, stream>>>(
        xb, Wg1, Call, nullptr, nullptr, FF,
        FF, FF, (int)CROW, NF, 0, NN * CROW);

    if (full) {
        // 4) E[n,m] = exp2(Y[n,:]·X[m,:]); Dsum colsums. (8,8,8) = 512 blocks
        gemm256<8, 2><<<dim3(NN / 256, NN / 256, BB), blk5, 0, stream>>>(
            Call, xb, E, nullptr, Dsum, FF,
            (int)CROW, FF, NN, NN * CROW, NF, NN2);
        // 5) supT[o,m] = sup[m,o]/D[m]
        scale_transpose<<<dim3(NN / 32, FF / 32, BB), blk, 0, stream>>>(Call, Dsum, supT, 0);
        // 6) out = E·supT + bias : BM=128, (2,16,8) = 256 blocks, 1 round
        gemm256<4, 0><<<dim3(FF / 256, NN / 128, BB), blk5, 0, stream>>>(
            E, supT, out, bias, nullptr, NN,
            NN, NN, FF, NN2, NF, NF);
    } else {
        for (int b = 0; b < BB; ++b) {
            const unsigned short* Cb = Call + (size_t)b * NN * CROW;
            gemm256<8, 2><<<dim3(NN / 256, NN / 256, 1), blk5, 0, stream>>>(
                Cb, xb + (size_t)b * NF, E, nullptr, Dsum + (size_t)b * NN, FF,
                (int)CROW, FF, NN, 0, 0, 0);
            scale_transpose<<<dim3(NN / 32, FF / 32, 1), blk, 0, stream>>>(Call, Dsum, supT, b);
            gemm256<4, 0><<<dim3(FF / 256, NN / 128, 1), blk5, 0, stream>>>(
                E, supT + (size_t)b * NF, out + (size_t)b * NF, bias, nullptr, NN,
                NN, NN, FF, 0, 0, 0);
        }
    }
}